// Round 6
// baseline (18620.827 us; speedup 1.0000x reference)
//
// v3.2 — identical semantics to v3/v3.1; resubmit after 3x UnresponsiveContainer.
#include <hip/hip_runtime.h>

#define B_  2
#define S_  2048
#define D_  2048
#define H_  16
#define DH_ 128
#define L_  512
#define M_  (B_*S_)

typedef float f32x4 __attribute__((ext_vector_type(4)));

// ---------------------------------------------------------------------------
// Generic C[M][N] = A[M][K] @ B[N][K]^T, f32 in/out/accum.
// 64x64 tile, 256 threads, 4x4 micro-tile, BK=16.  M%64==0, N%64==0, K%16==0.
// ---------------------------------------------------------------------------
#define BM 64
#define BN 64
#define BK 16

__global__ __launch_bounds__(256) void gemm_bt(const float* __restrict__ A,
                                               const float* __restrict__ Bmat,
                                               float* __restrict__ C,
                                               int M, int N, int K) {
    __shared__ float As[BK][BM + 1];
    __shared__ float Bs[BK][BN + 1];
    const int tid = threadIdx.x;
    const int bm = blockIdx.y * BM;
    const int bn = blockIdx.x * BN;
    const int tx = tid & 15;
    const int ty = tid >> 4;

    float acc[4][4] = {};

    const int lm = tid >> 2;          // 0..63  row within tile
    const int lk = (tid & 3) * 4;     // 0,4,8,12 k-offset (float4)

    for (int k0 = 0; k0 < K; k0 += BK) {
        f32x4 a4 = *reinterpret_cast<const f32x4*>(&A[(size_t)(bm + lm) * K + k0 + lk]);
        f32x4 b4 = *reinterpret_cast<const f32x4*>(&Bmat[(size_t)(bn + lm) * K + k0 + lk]);
#pragma unroll
        for (int j = 0; j < 4; ++j) {
            As[lk + j][lm] = a4[j];
            Bs[lk + j][lm] = b4[j];
        }
        __syncthreads();
#pragma unroll
        for (int kk = 0; kk < BK; ++kk) {
            float a[4], b[4];
#pragma unroll
            for (int i = 0; i < 4; ++i) a[i] = As[kk][ty * 4 + i];
#pragma unroll
            for (int j = 0; j < 4; ++j) b[j] = Bs[kk][tx * 4 + j];
#pragma unroll
            for (int i = 0; i < 4; ++i)
#pragma unroll
                for (int j = 0; j < 4; ++j) acc[i][j] += a[i] * b[j];
        }
        __syncthreads();
    }

#pragma unroll
    for (int i = 0; i < 4; ++i)
#pragma unroll
        for (int j = 0; j < 4; ++j) {
            int m = bm + ty * 4 + i;
            int n = bn + tx * 4 + j;
            C[(size_t)m * N + n] = acc[i][j];
        }
}

// ---------------------------------------------------------------------------
// LayerNorm over L=512 per row, f32.
// ---------------------------------------------------------------------------
__global__ __launch_bounds__(256) void ln_kernel(const float* __restrict__ pre,
                                                 const float* __restrict__ w,
                                                 const float* __restrict__ bias,
                                                 float* __restrict__ out) {
    const int row = blockIdx.x;
    const int tid = threadIdx.x;
    __shared__ float red[256];
    const size_t base = (size_t)row * L_;

    float x0 = pre[base + tid];
    float x1 = pre[base + tid + 256];

    red[tid] = x0 + x1;
    __syncthreads();
    for (int o = 128; o; o >>= 1) {
        if (tid < o) red[tid] += red[tid + o];
        __syncthreads();
    }
    float mu = red[0] * (1.0f / L_);
    __syncthreads();

    float d0 = x0 - mu, d1 = x1 - mu;
    red[tid] = d0 * d0 + d1 * d1;
    __syncthreads();
    for (int o = 128; o; o >>= 1) {
        if (tid < o) red[tid] += red[tid + o];
        __syncthreads();
    }
    float rstd = rsqrtf(red[0] * (1.0f / L_) + 1e-5f);

    out[base + tid]       = d0 * rstd * w[tid]       + bias[tid];
    out[base + tid + 256] = d1 * rstd * w[tid + 256] + bias[tid + 256];
}

// ---------------------------------------------------------------------------
// Attention for ONE batch: one block (256 thr) per (h,s) query row.
//   tmp[l] = sum_d q[s,h,d] * W_uk[h*128+d][l]
//   sc[t]  = dot(tmp, ckv[t,:]) / sqrt(128), t<=s;  softmax
//   ctx[s,h,d] = sum_t attn[t] * v[t,h,d]
// ---------------------------------------------------------------------------
__global__ __launch_bounds__(256) void attn_kernel(const float* __restrict__ q,
                                                   const float* __restrict__ ckv,
                                                   const float* __restrict__ vv,
                                                   const float* __restrict__ Wuk,
                                                   float* __restrict__ ctx) {
    const int bid = blockIdx.x;
    const int h = bid / S_;
    const int s = bid % S_;
    const int tid = threadIdx.x;

    __shared__ float qrow[DH_];
    __shared__ float tmp[L_];
    __shared__ float sc[S_];
    __shared__ float red[256];
    __shared__ float part[2][DH_];

    const size_t qbase = (size_t)s * D_ + h * DH_;
    if (tid < DH_) qrow[tid] = q[qbase + tid];
    __syncthreads();

    // absorbed-key row: tmp (512)
#pragma unroll
    for (int lo = 0; lo < 2; ++lo) {
        int l = tid + lo * 256;
        float acc = 0.f;
        for (int d = 0; d < DH_; ++d)
            acc += qrow[d] * Wuk[(size_t)(h * DH_ + d) * L_ + l];
        tmp[l] = acc;
    }
    __syncthreads();

    // scores over t <= s
    const float scale = 0.08838834764831845f;  // 1/sqrt(128)
    float lmax = -1e30f;
    for (int t = tid; t <= s; t += 256) {
        const f32x4* cp = reinterpret_cast<const f32x4*>(&ckv[(size_t)t * L_]);
        float acc = 0.f;
        for (int i = 0; i < L_ / 4; ++i) {
            f32x4 c4 = cp[i];
#pragma unroll
            for (int j = 0; j < 4; ++j) acc += tmp[i * 4 + j] * c4[j];
        }
        float val = acc * scale;
        sc[t] = val;
        lmax = fmaxf(lmax, val);
    }
    red[tid] = lmax;
    __syncthreads();
    for (int o = 128; o; o >>= 1) {
        if (tid < o) red[tid] = fmaxf(red[tid], red[tid + o]);
        __syncthreads();
    }
    float mx = red[0];
    __syncthreads();

    float lsum = 0.f;
    for (int t = tid; t <= s; t += 256) {
        float e = __expf(sc[t] - mx);
        sc[t] = e;
        lsum += e;
    }
    red[tid] = lsum;
    __syncthreads();
    for (int o = 128; o; o >>= 1) {
        if (tid < o) red[tid] += red[tid + o];
        __syncthreads();
    }
    float inv = 1.0f / red[0];
    __syncthreads();

    // ctx: 2 halves of t-range, 128 dims each
    const int d = tid & (DH_ - 1);
    const int half = tid >> 7;
    float acc = 0.f;
    for (int t = half; t <= s; t += 2)
        acc += sc[t] * vv[(size_t)t * D_ + h * DH_ + d];
    part[half][d] = acc;
    __syncthreads();
    if (tid < DH_)
        ctx[(size_t)s * D_ + h * DH_ + tid] =
            (part[0][tid] + part[1][tid]) * inv;
}

// ---------------------------------------------------------------------------
// All I/O f32. ws: q_b 16MB | v_b 16MB | ctx_b 16MB = 48 MB.
// ckv_pre (M*L f32 = 8.4MB) lives in the d_out head (dead before final GEMMs).
// ---------------------------------------------------------------------------
extern "C" void kernel_launch(void* const* d_in, const int* in_sizes, int n_in,
                              void* d_out, int out_size, void* d_ws, size_t ws_size,
                              hipStream_t stream) {
    const float* x    = (const float*)d_in[0];
    const float* Wq   = (const float*)d_in[1];
    const float* Wdkv = (const float*)d_in[2];
    const float* Wuk  = (const float*)d_in[3];
    const float* Wuv  = (const float*)d_in[4];
    const float* Wo   = (const float*)d_in[5];
    const float* lnw  = (const float*)d_in[6];
    const float* lnb  = (const float*)d_in[7];

    float* out = (float*)d_out;                 // (M, D)
    float* ckv = out + (size_t)M_ * D_;         // (M, L) — second tuple output

    float* ckvp = out;                          // (M, L) scratch in d_out head

    char* ws = (char*)d_ws;
    float* qb   = (float*)(ws);                          // (S, D) f32 = 16 MB
    float* vb   = (float*)(ws + (size_t)16777216);       // (S, D) f32 = 16 MB
    float* ctxb = (float*)(ws + (size_t)2 * 16777216);   // (S, D) f32 = 16 MB

    dim3 blk(256);

    // c_kv_pre = x @ W_dkv^T   (M=4096, N=512, K=2048) -> d_out head scratch
    gemm_bt<<<dim3(L_ / BN, M_ / BM), blk, 0, stream>>>(x, Wdkv, ckvp, M_, L_, D_);
    // c_kv = LN(c_kv_pre) -> d_out tail (real output)
    ln_kernel<<<dim3(M_), blk, 0, stream>>>(ckvp, lnw, lnb, ckv);

    for (int b = 0; b < B_; ++b) {
        const float* xb   = x   + (size_t)b * S_ * D_;
        const float* ckvb = ckv + (size_t)b * S_ * L_;
        float*       outb = out + (size_t)b * S_ * D_;

        // q_b = x_b @ W_q^T        (2048 x 2048, K=2048)
        gemm_bt<<<dim3(D_ / BN, S_ / BM), blk, 0, stream>>>(xb, Wq, qb, S_, D_, D_);
        // v_b = ckv_b @ W_uv^T     (2048 x 2048, K=512)
        gemm_bt<<<dim3(D_ / BN, S_ / BM), blk, 0, stream>>>(ckvb, Wuv, vb, S_, D_, L_);
        // attention -> ctx_b
        attn_kernel<<<dim3(H_ * S_), blk, 0, stream>>>(qb, ckvb, vb, Wuk, ctxb);
        // out_b = ctx_b @ W_o^T    (2048 x 2048, K=2048)
        gemm_bt<<<dim3(D_ / BN, S_ / BM), blk, 0, stream>>>(ctxb, Wo, outb, S_, D_, D_);
    }
}

// Round 7
// 2570.342 us; speedup vs baseline: 7.2445x; 7.2445x over previous
//
#include <hip/hip_runtime.h>

#define B_  2
#define S_  2048
#define D_  2048
#define H_  16
#define DH_ 128
#define L_  512
#define M_  (B_*S_)

typedef unsigned short u16;
typedef float f32x4 __attribute__((ext_vector_type(4)));
typedef short short8 __attribute__((ext_vector_type(8)));
typedef u16 u16x4 __attribute__((ext_vector_type(4)));
typedef u16 u16x8 __attribute__((ext_vector_type(8)));

__device__ inline float bf2f(u16 u) {
    union { unsigned int i; float f; } x; x.i = ((unsigned int)u) << 16; return x.f;
}
__device__ inline u16 f2bf(float f) {
    union { float f; unsigned int i; } x; x.f = f;
    unsigned int r = x.i + 0x7FFFu + ((x.i >> 16) & 1u);
    return (u16)(r >> 16);
}
__device__ inline f32x4 mfma16(short8 a, short8 b, f32x4 c) {
    return __builtin_amdgcn_mfma_f32_16x16x32_bf16(a, b, c, 0, 0, 0);
}

// ---------------------------------------------------------------------------
// Templated C[M][N] = A[M][K] @ B[N][K]^T.  TA/TB/TC in {float, u16(bf16)}.
// f32 accumulate.  64x64 tile, 256 thr, 4x4 micro-tile, BK=16.
// ---------------------------------------------------------------------------
#define BM 64
#define BN 64
#define BK 16

template <typename T> __device__ inline f32x4 load4(const T* p);
template <> __device__ inline f32x4 load4<float>(const float* p) {
    return *reinterpret_cast<const f32x4*>(p);
}
template <> __device__ inline f32x4 load4<u16>(const u16* p) {
    u16x4 v = *reinterpret_cast<const u16x4*>(p);
    f32x4 r; r[0]=bf2f(v[0]); r[1]=bf2f(v[1]); r[2]=bf2f(v[2]); r[3]=bf2f(v[3]);
    return r;
}
template <typename T> __device__ inline void store1(T* p, float v);
template <> __device__ inline void store1<float>(float* p, float v) { *p = v; }
template <> __device__ inline void store1<u16>(u16* p, float v) { *p = f2bf(v); }

template <typename TA, typename TB, typename TC>
__global__ __launch_bounds__(256) void gemm_bt(const TA* __restrict__ A,
                                               const TB* __restrict__ Bmat,
                                               TC* __restrict__ C,
                                               int M, int N, int K) {
    __shared__ float As[BK][BM + 1];
    __shared__ float Bs[BK][BN + 1];
    const int tid = threadIdx.x;
    const int bm = blockIdx.y * BM;
    const int bn = blockIdx.x * BN;
    const int tx = tid & 15;
    const int ty = tid >> 4;

    float acc[4][4] = {};
    const int lm = tid >> 2;
    const int lk = (tid & 3) * 4;

    for (int k0 = 0; k0 < K; k0 += BK) {
        f32x4 a4 = load4<TA>(&A[(size_t)(bm + lm) * K + k0 + lk]);
        f32x4 b4 = load4<TB>(&Bmat[(size_t)(bn + lm) * K + k0 + lk]);
#pragma unroll
        for (int j = 0; j < 4; ++j) { As[lk + j][lm] = a4[j]; Bs[lk + j][lm] = b4[j]; }
        __syncthreads();
#pragma unroll
        for (int kk = 0; kk < BK; ++kk) {
            float a[4], b[4];
#pragma unroll
            for (int i = 0; i < 4; ++i) a[i] = As[kk][ty * 4 + i];
#pragma unroll
            for (int j = 0; j < 4; ++j) b[j] = Bs[kk][tx * 4 + j];
#pragma unroll
            for (int i = 0; i < 4; ++i)
#pragma unroll
                for (int j = 0; j < 4; ++j) acc[i][j] += a[i] * b[j];
        }
        __syncthreads();
    }
#pragma unroll
    for (int i = 0; i < 4; ++i)
#pragma unroll
        for (int j = 0; j < 4; ++j)
            store1<TC>(&C[(size_t)(bm + ty*4 + i) * N + bn + tx*4 + j], acc[i][j]);
}

// ---------------------------------------------------------------------------
// LayerNorm over L=512 per row, f32.
// ---------------------------------------------------------------------------
__global__ __launch_bounds__(256) void ln_kernel(const float* __restrict__ pre,
                                                 const float* __restrict__ w,
                                                 const float* __restrict__ bias,
                                                 float* __restrict__ out) {
    const int row = blockIdx.x;
    const int tid = threadIdx.x;
    __shared__ float red[256];
    const size_t base = (size_t)row * L_;
    float x0 = pre[base + tid];
    float x1 = pre[base + tid + 256];
    red[tid] = x0 + x1;
    __syncthreads();
    for (int o = 128; o; o >>= 1) { if (tid < o) red[tid] += red[tid + o]; __syncthreads(); }
    float mu = red[0] * (1.0f / L_);
    __syncthreads();
    float d0 = x0 - mu, d1 = x1 - mu;
    red[tid] = d0 * d0 + d1 * d1;
    __syncthreads();
    for (int o = 128; o; o >>= 1) { if (tid < o) red[tid] += red[tid + o]; __syncthreads(); }
    float rstd = rsqrtf(red[0] * (1.0f / L_) + 1e-5f);
    out[base + tid]       = d0 * rstd * w[tid]       + bias[tid];
    out[base + tid + 256] = d1 * rstd * w[tid + 256] + bias[tid + 256];
}

// ---------------------------------------------------------------------------
// f32 -> bf16 convert (4 elems/thread)
// ---------------------------------------------------------------------------
__global__ __launch_bounds__(256) void cvt_bf16(const float* __restrict__ in,
                                                u16* __restrict__ out) {
    size_t i = ((size_t)blockIdx.x * 256 + threadIdx.x) * 4;
    f32x4 v = *reinterpret_cast<const f32x4*>(&in[i]);
    u16x4 o; o[0]=f2bf(v[0]); o[1]=f2bf(v[1]); o[2]=f2bf(v[2]); o[3]=f2bf(v[3]);
    *reinterpret_cast<u16x4*>(&out[i]) = o;
}

// ---------------------------------------------------------------------------
// absorb: q'[hh][s][l] = sum_d qb[s][h0col + hh*128 + d] * Wuk[hh*128+d][l]
// MFMA 16x16x32 bf16. grid (st=32, lt=8, hh=8), block 256 (4 waves).
// Tile 64(s) x 64(l), K=128 staged fully.
// ---------------------------------------------------------------------------
__global__ __launch_bounds__(256) void absorb(const u16* __restrict__ qb,
                                              const float* __restrict__ Wuk,
                                              u16* __restrict__ qp,
                                              int h0col) {
    const int st = blockIdx.x, lt = blockIdx.y, hh = blockIdx.z;
    const int tid = threadIdx.x;
    const int w = tid >> 6, l = tid & 63;
    const int g = l >> 4, ln16 = l & 15;

    __shared__ char A_lds[16384];   // [64 s][128 k] bf16, swz ^((row&7)<<4)
    __shared__ char B_lds[16384];   // [64 l][128 k] bf16 (transposed), swz

    // stage A (1024 u16x8 chunks)
#pragma unroll
    for (int i = 0; i < 4; ++i) {
        int idx = tid + i * 256;
        int row = idx >> 4, c8 = idx & 15;
        int byte = (row * 256 + c8 * 16) ^ ((row & 7) << 4);
        *reinterpret_cast<u16x8*>(A_lds + byte) =
            *reinterpret_cast<const u16x8*>(qb + (size_t)(st*64 + row) * D_ + h0col + hh*128 + c8*8);
    }
    // stage B transposed (8192 scalars)
#pragma unroll
    for (int i = 0; i < 32; ++i) {
        int idx = tid + i * 256;
        int k = idx >> 6, n = idx & 63;
        int byte = (n * 256 + k * 2) ^ ((n & 7) << 4);
        *reinterpret_cast<u16*>(B_lds + byte) =
            f2bf(Wuk[(size_t)(hh*128 + k) * L_ + lt*64 + n]);
    }
    __syncthreads();

    f32x4 acc[4];
#pragma unroll
    for (int a = 0; a < 4; ++a) acc[a] = {0,0,0,0};

#pragma unroll
    for (int kc = 0; kc < 4; ++kc) {
        const int arow = w*16 + ln16;
        short8 af = *reinterpret_cast<const short8*>(
            A_lds + ((arow*256 + kc*64 + g*16) ^ ((arow & 7) << 4)));
#pragma unroll
        for (int a = 0; a < 4; ++a) {
            const int brow = a*16 + ln16;
            short8 bf = *reinterpret_cast<const short8*>(
                B_lds + ((brow*256 + kc*64 + g*16) ^ ((brow & 7) << 4)));
            acc[a] = mfma16(af, bf, acc[a]);
        }
    }
#pragma unroll
    for (int a = 0; a < 4; ++a)
#pragma unroll
        for (int r = 0; r < 4; ++r)
            qp[((size_t)hh * S_ + st*64 + w*16 + g*4 + r) * L_ + lt*64 + a*16 + ln16] =
                f2bf(acc[a][r]);
}

// ---------------------------------------------------------------------------
// flash attention: grid (qt=32, hh=8), block 256 (4 waves, 16 q-rows each).
// KV tile 64.  K_lds [64][512] bf16 swz; V_lds transposed [128 dv][64 kv] swz;
// P_lds per-wave [16 q][64 kv] swz.  Swapped QK^T (A=K, B=Q') so softmax rows
// are lane-local (q = lane&15).  f32 online-softmax state + ctx accum.
// ---------------------------------------------------------------------------
__global__ __launch_bounds__(256) void flash_attn(const u16* __restrict__ qp,
                                                  const u16* __restrict__ kbf,
                                                  const u16* __restrict__ vbf,
                                                  u16* __restrict__ ctx,
                                                  int h0) {
    const int qt = blockIdx.x;
    const int hh = blockIdx.y;
    const int h = h0 + hh;
    const int tid = threadIdx.x;
    const int w = tid >> 6, l = tid & 63;
    const int g = l >> 4, ln16 = l & 15;

    __shared__ char K_lds[65536];
    __shared__ char V_lds[16384];
    __shared__ char P_lds[8192];
    char* P_my = P_lds + w * 2048;

    // per-lane Q' registers: row = qt*64 + w*16 + ln16
    short8 qreg[16];
    {
        const u16* qbase = qp + ((size_t)hh * S_ + qt*64 + w*16 + ln16) * L_ + g*8;
#pragma unroll
        for (int kc = 0; kc < 16; ++kc)
            qreg[kc] = *reinterpret_cast<const short8*>(qbase + kc*32);
    }

    float m_run = -1e30f, l_run = 0.f;
    f32x4 acc[8];
#pragma unroll
    for (int c = 0; c < 8; ++c) acc[c] = {0,0,0,0};

    const int sq = qt*64 + w*16 + ln16;      // lane's q row (softmax phase)
    const float scale = 0.08838834764831845f;

    for (int kt = 0; kt <= qt; ++kt) {
        __syncthreads();
        // stage K tile (64 x 512 bf16 = 4096 x 16B)
        {
            const u16* src = kbf + (size_t)kt * 64 * L_;
#pragma unroll
            for (int i = 0; i < 16; ++i) {
                int idx = tid + i * 256;
                int row = idx >> 6, c8 = idx & 63;
                int byte = (row * 1024 + c8 * 16) ^ ((row & 7) << 4);
                *reinterpret_cast<u16x8*>(K_lds + byte) =
                    *reinterpret_cast<const u16x8*>(src + (size_t)row * L_ + c8 * 8);
            }
        }
        // stage V tile transposed: V_lds[dv][kv]
        {
            const u16* src = vbf + (size_t)kt * 64 * D_ + h * DH_;
#pragma unroll
            for (int i = 0; i < 32; ++i) {
                int idx = tid + i * 256;
                int dv = idx & 127, kv = idx >> 7;
                int byte = (dv * 128 + kv * 2) ^ ((dv & 7) << 4);
                *reinterpret_cast<u16*>(V_lds + byte) = src[(size_t)kv * D_ + dv];
            }
        }
        __syncthreads();

        // QK^T swapped: D[kv][q]
        f32x4 sacc[4];
#pragma unroll
        for (int a = 0; a < 4; ++a) sacc[a] = {0,0,0,0};
#pragma unroll
        for (int a = 0; a < 4; ++a) {
            const int row = a*16 + ln16;
            const int rs = (row & 7) << 4;
#pragma unroll
            for (int kc = 0; kc < 16; ++kc) {
                short8 kf = *reinterpret_cast<const short8*>(
                    K_lds + ((row*1024 + kc*64 + g*16) ^ rs));
                sacc[a] = mfma16(kf, qreg[kc], sacc[a]);
            }
        }

        // online softmax (lane owns q = ln16; 16 kv values at a*16+g*4+r)
        float p[4][4];
        float tmax = -1e30f;
#pragma unroll
        for (int a = 0; a < 4; ++a)
#pragma unroll
            for (int r = 0; r < 4; ++r) {
                int t = kt*64 + a*16 + g*4 + r;
                float v = (t <= sq) ? sacc[a][r] * scale : -1e30f;
                p[a][r] = v;
                tmax = fmaxf(tmax, v);
            }
        tmax = fmaxf(tmax, __shfl_xor(tmax, 16, 64));
        tmax = fmaxf(tmax, __shfl_xor(tmax, 32, 64));
        float m_new = fmaxf(m_run, tmax);
        float fac = __expf(m_run - m_new);
        float rsum = 0.f;
#pragma unroll
        for (int a = 0; a < 4; ++a)
#pragma unroll
            for (int r = 0; r < 4; ++r) {
                float e = __expf(p[a][r] - m_new);
                p[a][r] = e;
                rsum += e;
            }
        rsum += __shfl_xor(rsum, 16, 64);
        rsum += __shfl_xor(rsum, 32, 64);
        l_run = l_run * fac + rsum;
        m_run = m_new;

        // write P (bf16) to wave-local LDS: row q=ln16, cols a*16+g*4+(0..3)
        {
            const int ps = (ln16 & 7) << 4;
#pragma unroll
            for (int a = 0; a < 4; ++a) {
                u16x4 quad;
#pragma unroll
                for (int r = 0; r < 4; ++r) quad[r] = f2bf(p[a][r]);
                *reinterpret_cast<u16x4*>(P_my + ((ln16*128 + a*32 + g*8) ^ ps)) = quad;
            }
        }
        // rescale ctx acc (ctx rows q = g*4+reg -> fetch factor by shuffle)
        float fr[4];
#pragma unroll
        for (int r = 0; r < 4; ++r) fr[r] = __shfl(fac, g*4 + r, 64);
#pragma unroll
        for (int c = 0; c < 8; ++c)
#pragma unroll
            for (int r = 0; r < 4; ++r) acc[c][r] *= fr[r];

        // PV: A = P (16q x 64kv), B = V (64kv x 128dv)
#pragma unroll
        for (int kc2 = 0; kc2 < 2; ++kc2) {
            short8 pf = *reinterpret_cast<const short8*>(
                P_my + ((ln16*128 + kc2*64 + g*16) ^ ((ln16 & 7) << 4)));
#pragma unroll
            for (int c = 0; c < 8; ++c) {
                const int dv = c*16 + ln16;
                short8 vf = *reinterpret_cast<const short8*>(
                    V_lds + ((dv*128 + kc2*64 + g*16) ^ ((dv & 7) << 4)));
                acc[c] = mfma16(pf, vf, acc[c]);
            }
        }
    }

    // epilogue: normalize + write ctx (rows q = g*4+reg)
    float inv = 1.0f / l_run;
    float ir[4];
#pragma unroll
    for (int r = 0; r < 4; ++r) ir[r] = __shfl(inv, g*4 + r, 64);
#pragma unroll
    for (int c = 0; c < 8; ++c)
#pragma unroll
        for (int r = 0; r < 4; ++r) {
            int srow = qt*64 + w*16 + g*4 + r;
            ctx[(size_t)srow * D_ + h*DH_ + c*16 + ln16] = f2bf(acc[c][r] * ir[r]);
        }
}

// ---------------------------------------------------------------------------
// ws (44 MB): qb_bf 8M | qprime 16M | vb_bf 8M | ckv_bf 4M | ctx_bf 8M
// ckv_pre f32 lives in d_out head (dead before final GEMMs).
// ---------------------------------------------------------------------------
extern "C" void kernel_launch(void* const* d_in, const int* in_sizes, int n_in,
                              void* d_out, int out_size, void* d_ws, size_t ws_size,
                              hipStream_t stream) {
    const float* x    = (const float*)d_in[0];
    const float* Wq   = (const float*)d_in[1];
    const float* Wdkv = (const float*)d_in[2];
    const float* Wuk  = (const float*)d_in[3];
    const float* Wuv  = (const float*)d_in[4];
    const float* Wo   = (const float*)d_in[5];
    const float* lnw  = (const float*)d_in[6];
    const float* lnb  = (const float*)d_in[7];

    float* out = (float*)d_out;
    float* ckv = out + (size_t)M_ * D_;          // (M, L) second tuple output
    float* ckvp = out;                            // scratch in d_out head

    char* ws = (char*)d_ws;
    u16* qb_bf  = (u16*)(ws);                            // 8 MB
    u16* qprime = (u16*)(ws + (size_t)8388608);          // 16 MB
    u16* vb_bf  = (u16*)(ws + (size_t)25165824);         // 8 MB
    u16* ckv_bf = (u16*)(ws + (size_t)33554432);         // 4 MB (both batches)
    u16* ctx_bf = (u16*)(ws + (size_t)37748736);         // 8 MB

    dim3 blk(256);

    // c_kv_pre = x @ W_dkv^T -> d_out head scratch
    gemm_bt<float,float,float><<<dim3(L_/BN, M_/BM), blk, 0, stream>>>(x, Wdkv, ckvp, M_, L_, D_);
    // c_kv = LN -> d_out tail
    ln_kernel<<<dim3(M_), blk, 0, stream>>>(ckvp, lnw, lnb, ckv);
    // ckv -> bf16
    cvt_bf16<<<dim3((M_*L_)/1024), blk, 0, stream>>>(ckv, ckv_bf);

    for (int b = 0; b < B_; ++b) {
        const float* xb    = x   + (size_t)b * S_ * D_;
        const float* ckvfb = ckv + (size_t)b * S_ * L_;
        const u16*   ckvbb = ckv_bf + (size_t)b * S_ * L_;
        float*       outb  = out + (size_t)b * S_ * D_;

        // q_b (bf16 out)
        gemm_bt<float,float,u16><<<dim3(D_/BN, S_/BM), blk, 0, stream>>>(xb, Wq, qb_bf, S_, D_, D_);
        // v_b (bf16 out)
        gemm_bt<float,float,u16><<<dim3(D_/BN, S_/BM), blk, 0, stream>>>(ckvfb, Wuv, vb_bf, S_, D_, L_);

        for (int hc = 0; hc < 2; ++hc) {
            absorb<<<dim3(S_/64, L_/64, 8), blk, 0, stream>>>(
                qb_bf, Wuk + (size_t)hc * 8 * DH_ * L_, qprime, hc * 8 * DH_);
            flash_attn<<<dim3(S_/64, 8), blk, 0, stream>>>(
                qprime, ckvbb, vb_bf, ctx_bf, hc * 8);
        }
        // out_b = ctx @ W_o^T (bf16 A, f32 B/C)
        gemm_bt<u16,float,float><<<dim3(D_/BN, S_/BM), blk, 0, stream>>>(ctx_bf, Wo, outb, S_, D_, D_);
    }
}

// Round 8
// 1350.759 us; speedup vs baseline: 13.7855x; 1.9029x over previous
//
#include <hip/hip_runtime.h>

#define B_  2
#define S_  2048
#define D_  2048
#define H_  16
#define DH_ 128
#define L_  512
#define M_  (B_*S_)

typedef unsigned short u16;
typedef float f32x4 __attribute__((ext_vector_type(4)));
typedef short short8 __attribute__((ext_vector_type(8)));
typedef u16 u16x4 __attribute__((ext_vector_type(4)));
typedef u16 u16x8 __attribute__((ext_vector_type(8)));

__device__ inline float bf2f(u16 u) {
    union { unsigned int i; float f; } x; x.i = ((unsigned int)u) << 16; return x.f;
}
__device__ inline u16 f2bf(float f) {
    union { float f; unsigned int i; } x; x.f = f;
    unsigned int r = x.i + 0x7FFFu + ((x.i >> 16) & 1u);
    return (u16)(r >> 16);
}
__device__ inline f32x4 mfma16(short8 a, short8 b, f32x4 c) {
    return __builtin_amdgcn_mfma_f32_16x16x32_bf16(a, b, c, 0, 0, 0);
}

typedef const __attribute__((address_space(1))) unsigned int gu32;
typedef __attribute__((address_space(3))) unsigned int lu32;
__device__ inline void gload16(const u16* g, u16* l) {
    __builtin_amdgcn_global_load_lds((gu32*)g, (lu32*)l, 16, 0, 0);
}

template <typename T> __device__ inline void store1(T* p, float v);
template <> __device__ inline void store1<float>(float* p, float v) { *p = v; }
template <> __device__ inline void store1<u16>(u16* p, float v) { *p = f2bf(v); }

// ---------------------------------------------------------------------------
// MFMA GEMM: C[M][N] = A[M][K] @ B[N][K]^T, A/B bf16, f32 accum, TC out.
// 128x128 tile, 4 waves (64x64 each), BK=32, global_load_lds staging.
// LDS layout k-outer: [koff 0..3][row 0..127][8 bf16] -> conflict-free b128.
// grid = (N/128, M/128). M,N %128==0, K%32==0.
// ---------------------------------------------------------------------------
template <typename TC>
__global__ __launch_bounds__(256) void mgemm(const u16* __restrict__ A,
                                             const u16* __restrict__ Bm,
                                             TC* __restrict__ C,
                                             int N, int K) {
    const int tid = threadIdx.x;
    const int bn = blockIdx.x * 128, bm = blockIdx.y * 128;
    const int w = tid >> 6, l = tid & 63;
    const int wr = w >> 1, wc = w & 1;
    const int g = l >> 4, ln16 = l & 15;

    __shared__ u16 A_lds[4096];     // [koff][row][8]
    __shared__ u16 B_lds[4096];

    f32x4 acc[4][4];
#pragma unroll
    for (int m = 0; m < 4; ++m)
#pragma unroll
        for (int n = 0; n < 4; ++n) acc[m][n] = {0.f, 0.f, 0.f, 0.f};

    const int c0 = tid, c1 = tid + 256;       // chunk ids; koff=c>>7, row=c&127
    const int r0 = c0 & 127, k0off = (c0 >> 7) * 8;
    const int r1 = c1 & 127, k1off = (c1 >> 7) * 8;

    for (int k0 = 0; k0 < K; k0 += 32) {
        __syncthreads();
        gload16(A  + (size_t)(bm + r0) * K + k0 + k0off, &A_lds[c0 * 8]);
        gload16(A  + (size_t)(bm + r1) * K + k0 + k1off, &A_lds[c1 * 8]);
        gload16(Bm + (size_t)(bn + r0) * K + k0 + k0off, &B_lds[c0 * 8]);
        gload16(Bm + (size_t)(bn + r1) * K + k0 + k1off, &B_lds[c1 * 8]);
        __syncthreads();

        short8 af[4], bf[4];
#pragma unroll
        for (int m = 0; m < 4; ++m)
            af[m] = *reinterpret_cast<const short8*>(&A_lds[g * 1024 + (wr*64 + m*16 + ln16) * 8]);
#pragma unroll
        for (int n = 0; n < 4; ++n)
            bf[n] = *reinterpret_cast<const short8*>(&B_lds[g * 1024 + (wc*64 + n*16 + ln16) * 8]);
#pragma unroll
        for (int m = 0; m < 4; ++m)
#pragma unroll
            for (int n = 0; n < 4; ++n)
                acc[m][n] = mfma16(af[m], bf[n], acc[m][n]);
    }

#pragma unroll
    for (int m = 0; m < 4; ++m)
#pragma unroll
        for (int n = 0; n < 4; ++n)
#pragma unroll
            for (int r = 0; r < 4; ++r)
                store1<TC>(&C[(size_t)(bm + wr*64 + m*16 + g*4 + r) * N + bn + wc*64 + n*16 + ln16],
                           acc[m][n][r]);
}

// ---------------------------------------------------------------------------
// LayerNorm over L=512 per row, f32.
// ---------------------------------------------------------------------------
__global__ __launch_bounds__(256) void ln_kernel(const float* __restrict__ pre,
                                                 const float* __restrict__ w,
                                                 const float* __restrict__ bias,
                                                 float* __restrict__ out) {
    const int row = blockIdx.x;
    const int tid = threadIdx.x;
    __shared__ float red[256];
    const size_t base = (size_t)row * L_;
    float x0 = pre[base + tid];
    float x1 = pre[base + tid + 256];
    red[tid] = x0 + x1;
    __syncthreads();
    for (int o = 128; o; o >>= 1) { if (tid < o) red[tid] += red[tid + o]; __syncthreads(); }
    float mu = red[0] * (1.0f / L_);
    __syncthreads();
    float d0 = x0 - mu, d1 = x1 - mu;
    red[tid] = d0 * d0 + d1 * d1;
    __syncthreads();
    for (int o = 128; o; o >>= 1) { if (tid < o) red[tid] += red[tid + o]; __syncthreads(); }
    float rstd = rsqrtf(red[0] * (1.0f / L_) + 1e-5f);
    out[base + tid]       = d0 * rstd * w[tid]       + bias[tid];
    out[base + tid + 256] = d1 * rstd * w[tid + 256] + bias[tid + 256];
}

// ---------------------------------------------------------------------------
// f32 -> bf16 convert (4 elems/thread)
// ---------------------------------------------------------------------------
__global__ __launch_bounds__(256) void cvt_bf16(const float* __restrict__ in,
                                                u16* __restrict__ out) {
    size_t i = ((size_t)blockIdx.x * 256 + threadIdx.x) * 4;
    f32x4 v = *reinterpret_cast<const f32x4*>(&in[i]);
    u16x4 o; o[0]=f2bf(v[0]); o[1]=f2bf(v[1]); o[2]=f2bf(v[2]); o[3]=f2bf(v[3]);
    *reinterpret_cast<u16x4*>(&out[i]) = o;
}

// ---------------------------------------------------------------------------
// absorb: q'[hh][s][l] = sum_d qb[s][h0col + hh*128 + d] * Wuk[hh*128+d][l]
// MFMA 16x16x32 bf16. grid (st=32, lt=8, hh=8), block 256 (4 waves).
// ---------------------------------------------------------------------------
__global__ __launch_bounds__(256) void absorb(const u16* __restrict__ qb,
                                              const float* __restrict__ Wuk,
                                              u16* __restrict__ qp,
                                              int h0col) {
    const int st = blockIdx.x, lt = blockIdx.y, hh = blockIdx.z;
    const int tid = threadIdx.x;
    const int w = tid >> 6, l = tid & 63;
    const int g = l >> 4, ln16 = l & 15;

    __shared__ char A_lds[16384];   // [64 s][128 k] bf16, swz ^((row&7)<<4)
    __shared__ char B_lds[16384];   // [64 l][128 k] bf16 (transposed), swz

#pragma unroll
    for (int i = 0; i < 4; ++i) {
        int idx = tid + i * 256;
        int row = idx >> 4, c8 = idx & 15;
        int byte = (row * 256 + c8 * 16) ^ ((row & 7) << 4);
        *reinterpret_cast<u16x8*>(A_lds + byte) =
            *reinterpret_cast<const u16x8*>(qb + (size_t)(st*64 + row) * D_ + h0col + hh*128 + c8*8);
    }
#pragma unroll
    for (int i = 0; i < 32; ++i) {
        int idx = tid + i * 256;
        int k = idx >> 6, n = idx & 63;
        int byte = (n * 256 + k * 2) ^ ((n & 7) << 4);
        *reinterpret_cast<u16*>(B_lds + byte) =
            f2bf(Wuk[(size_t)(hh*128 + k) * L_ + lt*64 + n]);
    }
    __syncthreads();

    f32x4 acc[4];
#pragma unroll
    for (int a = 0; a < 4; ++a) acc[a] = {0,0,0,0};

#pragma unroll
    for (int kc = 0; kc < 4; ++kc) {
        const int arow = w*16 + ln16;
        short8 af = *reinterpret_cast<const short8*>(
            A_lds + ((arow*256 + kc*64 + g*16) ^ ((arow & 7) << 4)));
#pragma unroll
        for (int a = 0; a < 4; ++a) {
            const int brow = a*16 + ln16;
            short8 bf = *reinterpret_cast<const short8*>(
                B_lds + ((brow*256 + kc*64 + g*16) ^ ((brow & 7) << 4)));
            acc[a] = mfma16(af, bf, acc[a]);
        }
    }
#pragma unroll
    for (int a = 0; a < 4; ++a)
#pragma unroll
        for (int r = 0; r < 4; ++r)
            qp[((size_t)hh * S_ + st*64 + w*16 + g*4 + r) * L_ + lt*64 + a*16 + ln16] =
                f2bf(acc[a][r]);
}

// ---------------------------------------------------------------------------
// flash attention: grid (qt=32, hh=8), block 256 (4 waves, 16 q-rows each).
// ---------------------------------------------------------------------------
__global__ __launch_bounds__(256) void flash_attn(const u16* __restrict__ qp,
                                                  const u16* __restrict__ kbf,
                                                  const u16* __restrict__ vbf,
                                                  u16* __restrict__ ctx,
                                                  int h0) {
    const int qt = blockIdx.x;
    const int hh = blockIdx.y;
    const int h = h0 + hh;
    const int tid = threadIdx.x;
    const int w = tid >> 6, l = tid & 63;
    const int g = l >> 4, ln16 = l & 15;

    __shared__ char K_lds[65536];
    __shared__ char V_lds[16384];
    __shared__ char P_lds[8192];
    char* P_my = P_lds + w * 2048;

    short8 qreg[16];
    {
        const u16* qbase = qp + ((size_t)hh * S_ + qt*64 + w*16 + ln16) * L_ + g*8;
#pragma unroll
        for (int kc = 0; kc < 16; ++kc)
            qreg[kc] = *reinterpret_cast<const short8*>(qbase + kc*32);
    }

    float m_run = -1e30f, l_run = 0.f;
    f32x4 acc[8];
#pragma unroll
    for (int c = 0; c < 8; ++c) acc[c] = {0,0,0,0};

    const int sq = qt*64 + w*16 + ln16;
    const float scale = 0.08838834764831845f;

    for (int kt = 0; kt <= qt; ++kt) {
        __syncthreads();
        {
            const u16* src = kbf + (size_t)kt * 64 * L_;
#pragma unroll
            for (int i = 0; i < 16; ++i) {
                int idx = tid + i * 256;
                int row = idx >> 6, c8 = idx & 63;
                int byte = (row * 1024 + c8 * 16) ^ ((row & 7) << 4);
                *reinterpret_cast<u16x8*>(K_lds + byte) =
                    *reinterpret_cast<const u16x8*>(src + (size_t)row * L_ + c8 * 8);
            }
        }
        {
            const u16* src = vbf + (size_t)kt * 64 * D_ + h * DH_;
#pragma unroll
            for (int i = 0; i < 32; ++i) {
                int idx = tid + i * 256;
                int dv = idx & 127, kv = idx >> 7;
                int byte = (dv * 128 + kv * 2) ^ ((dv & 7) << 4);
                *reinterpret_cast<u16*>(V_lds + byte) = src[(size_t)kv * D_ + dv];
            }
        }
        __syncthreads();

        f32x4 sacc[4];
#pragma unroll
        for (int a = 0; a < 4; ++a) sacc[a] = {0,0,0,0};
#pragma unroll
        for (int a = 0; a < 4; ++a) {
            const int row = a*16 + ln16;
            const int rs = (row & 7) << 4;
#pragma unroll
            for (int kc = 0; kc < 16; ++kc) {
                short8 kf = *reinterpret_cast<const short8*>(
                    K_lds + ((row*1024 + kc*64 + g*16) ^ rs));
                sacc[a] = mfma16(kf, qreg[kc], sacc[a]);
            }
        }

        float p[4][4];
        float tmax = -1e30f;
#pragma unroll
        for (int a = 0; a < 4; ++a)
#pragma unroll
            for (int r = 0; r < 4; ++r) {
                int t = kt*64 + a*16 + g*4 + r;
                float v = (t <= sq) ? sacc[a][r] * scale : -1e30f;
                p[a][r] = v;
                tmax = fmaxf(tmax, v);
            }
        tmax = fmaxf(tmax, __shfl_xor(tmax, 16, 64));
        tmax = fmaxf(tmax, __shfl_xor(tmax, 32, 64));
        float m_new = fmaxf(m_run, tmax);
        float fac = __expf(m_run - m_new);
        float rsum = 0.f;
#pragma unroll
        for (int a = 0; a < 4; ++a)
#pragma unroll
            for (int r = 0; r < 4; ++r) {
                float e = __expf(p[a][r] - m_new);
                p[a][r] = e;
                rsum += e;
            }
        rsum += __shfl_xor(rsum, 16, 64);
        rsum += __shfl_xor(rsum, 32, 64);
        l_run = l_run * fac + rsum;
        m_run = m_new;

        {
            const int ps = (ln16 & 7) << 4;
#pragma unroll
            for (int a = 0; a < 4; ++a) {
                u16x4 quad;
#pragma unroll
                for (int r = 0; r < 4; ++r) quad[r] = f2bf(p[a][r]);
                *reinterpret_cast<u16x4*>(P_my + ((ln16*128 + a*32 + g*8) ^ ps)) = quad;
            }
        }
        float fr[4];
#pragma unroll
        for (int r = 0; r < 4; ++r) fr[r] = __shfl(fac, g*4 + r, 64);
#pragma unroll
        for (int c = 0; c < 8; ++c)
#pragma unroll
            for (int r = 0; r < 4; ++r) acc[c][r] *= fr[r];

#pragma unroll
        for (int kc2 = 0; kc2 < 2; ++kc2) {
            short8 pf = *reinterpret_cast<const short8*>(
                P_my + ((ln16*128 + kc2*64 + g*16) ^ ((ln16 & 7) << 4)));
#pragma unroll
            for (int c = 0; c < 8; ++c) {
                const int dv = c*16 + ln16;
                short8 vf = *reinterpret_cast<const short8*>(
                    V_lds + ((dv*128 + kc2*64 + g*16) ^ ((dv & 7) << 4)));
                acc[c] = mfma16(pf, vf, acc[c]);
            }
        }
    }

    float inv = 1.0f / l_run;
    float ir[4];
#pragma unroll
    for (int r = 0; r < 4; ++r) ir[r] = __shfl(inv, g*4 + r, 64);
#pragma unroll
    for (int c = 0; c < 8; ++c)
#pragma unroll
        for (int r = 0; r < 4; ++r) {
            int srow = qt*64 + w*16 + g*4 + r;
            ctx[(size_t)srow * D_ + h*DH_ + c*16 + ln16] = f2bf(acc[c][r] * ir[r]);
        }
}

// ---------------------------------------------------------------------------
// ws (44 MB, proven budget):
//   [ 0,16) R1: xb_bf [0,8) + wslot [8,16)  -- later reused as qprime [0,16)
//   [16,24) qb_bf   [24,32) vb_bf   [32,36) ckv_bf (full M)   [36,44) ctx_bf
// ckv_pre f32 scratch lives in d_out at out_b1's region (dead before written).
// ---------------------------------------------------------------------------
extern "C" void kernel_launch(void* const* d_in, const int* in_sizes, int n_in,
                              void* d_out, int out_size, void* d_ws, size_t ws_size,
                              hipStream_t stream) {
    const float* x    = (const float*)d_in[0];
    const float* Wq   = (const float*)d_in[1];
    const float* Wdkv = (const float*)d_in[2];
    const float* Wuk  = (const float*)d_in[3];
    const float* Wuv  = (const float*)d_in[4];
    const float* Wo   = (const float*)d_in[5];
    const float* lnw  = (const float*)d_in[6];
    const float* lnb  = (const float*)d_in[7];

    float* out = (float*)d_out;
    float* ckv = out + (size_t)M_ * D_;               // (M, L) second output
    float* ckvp = out + (size_t)S_ * D_;              // scratch in out_b1 region

    char* ws = (char*)d_ws;
    u16* xb_bf  = (u16*)(ws);                          // 8 MB
    u16* wslot  = (u16*)(ws + (size_t)8388608);        // 8 MB
    u16* qprime = (u16*)(ws);                          // 16 MB (overlaps xb+wslot)
    u16* qb_bf  = (u16*)(ws + (size_t)16777216);       // 8 MB
    u16* vb_bf  = (u16*)(ws + (size_t)25165824);       // 8 MB
    u16* ckv_bf = (u16*)(ws + (size_t)33554432);       // 4 MB (full M)
    u16* ctx_bf = (u16*)(ws + (size_t)37748736);       // 8 MB

    dim3 blk(256);

    for (int b = 0; b < B_; ++b) {
        const float* xb     = x + (size_t)b * S_ * D_;
        float*       ckv_b  = ckv + (size_t)b * S_ * L_;
        u16*         ckvbf_b= ckv_bf + (size_t)b * S_ * L_;
        float*       outb   = out + (size_t)b * S_ * D_;

        // x_b -> bf16
        cvt_bf16<<<dim3(4096), blk, 0, stream>>>(xb, xb_bf);

        // ckv_pre_b = x_b @ Wdkv^T  (M=2048, N=512, K=2048)
        cvt_bf16<<<dim3(1024), blk, 0, stream>>>(Wdkv, wslot);
        mgemm<float><<<dim3(L_/128, S_/128), blk, 0, stream>>>(xb_bf, wslot, ckvp, L_, D_);
        ln_kernel<<<dim3(S_), blk, 0, stream>>>(ckvp, lnw, lnb, ckv_b);
        cvt_bf16<<<dim3(1024), blk, 0, stream>>>(ckv_b, ckvbf_b);

        // q_b = x_b @ Wq^T  (bf16 out)
        cvt_bf16<<<dim3(4096), blk, 0, stream>>>(Wq, wslot);
        mgemm<u16><<<dim3(D_/128, S_/128), blk, 0, stream>>>(xb_bf, wslot, qb_bf, D_, D_);

        // v_b = ckv_b @ Wuv^T  (bf16 out)   [xb_bf dead after this point]
        cvt_bf16<<<dim3(1024), blk, 0, stream>>>(Wuv, wslot);
        mgemm<u16><<<dim3(D_/128, S_/128), blk, 0, stream>>>(ckvbf_b, wslot, vb_bf, D_, L_);

        // attention (qprime clobbers xb_bf/wslot regions - both dead)
        for (int hc = 0; hc < 2; ++hc) {
            absorb<<<dim3(S_/64, L_/64, 8), blk, 0, stream>>>(
                qb_bf, Wuk + (size_t)hc * 8 * DH_ * L_, qprime, hc * 8 * DH_);
            flash_attn<<<dim3(S_/64, 8), blk, 0, stream>>>(
                qprime, ckvbf_b, vb_bf, ctx_bf, hc * 8);
        }

        // out_b = ctx @ Wo^T (f32 out)  [qprime dead; wslot reuse ok]
        cvt_bf16<<<dim3(4096), blk, 0, stream>>>(Wo, wslot);
        mgemm<float><<<dim3(D_/128, S_/128), blk, 0, stream>>>(ctx_bf, wslot, outb, D_, D_);
    }
}

// Round 10
// 976.861 us; speedup vs baseline: 19.0619x; 1.3828x over previous
//
// v5.1 — identical to v5 (round-8 submission); resubmit after UnresponsiveContainer.
#include <hip/hip_runtime.h>

#define B_  2
#define S_  2048
#define D_  2048
#define H_  16
#define DH_ 128
#define L_  512
#define M_  (B_*S_)

typedef unsigned short u16;
typedef float f32x4 __attribute__((ext_vector_type(4)));
typedef short short8 __attribute__((ext_vector_type(8)));
typedef u16 u16x4 __attribute__((ext_vector_type(4)));
typedef u16 u16x8 __attribute__((ext_vector_type(8)));

__device__ inline float bf2f(u16 u) {
    union { unsigned int i; float f; } x; x.i = ((unsigned int)u) << 16; return x.f;
}
__device__ inline u16 f2bf(float f) {
    union { float f; unsigned int i; } x; x.f = f;
    unsigned int r = x.i + 0x7FFFu + ((x.i >> 16) & 1u);
    return (u16)(r >> 16);
}
__device__ inline f32x4 mfma16(short8 a, short8 b, f32x4 c) {
    return __builtin_amdgcn_mfma_f32_16x16x32_bf16(a, b, c, 0, 0, 0);
}

typedef const __attribute__((address_space(1))) unsigned int gu32;
typedef __attribute__((address_space(3))) unsigned int lu32;
__device__ inline void gload16(const u16* g, u16* l) {
    __builtin_amdgcn_global_load_lds((gu32*)g, (lu32*)l, 16, 0, 0);
}

template <typename T> __device__ inline void store1(T* p, float v);
template <> __device__ inline void store1<float>(float* p, float v) { *p = v; }
template <> __device__ inline void store1<u16>(u16* p, float v) { *p = f2bf(v); }

// ---------------------------------------------------------------------------
// MFMA GEMM: C[M][N] = A[M][K] @ B[N][K]^T, A/B bf16, f32 accum, TC out.
// 128x128 tile, 4 waves, BK=32, global_load_lds, k-slice LDS layout.
// ---------------------------------------------------------------------------
template <typename TC>
__global__ __launch_bounds__(256) void mgemm(const u16* __restrict__ A,
                                             const u16* __restrict__ Bm,
                                             TC* __restrict__ C,
                                             int N, int K) {
    const int tid = threadIdx.x;
    const int bn = blockIdx.x * 128, bm = blockIdx.y * 128;
    const int w = tid >> 6, l = tid & 63;
    const int wr = w >> 1, wc = w & 1;
    const int g = l >> 4, ln16 = l & 15;

    __shared__ u16 A_lds[4096];     // [koff][row][8]
    __shared__ u16 B_lds[4096];

    f32x4 acc[4][4];
#pragma unroll
    for (int m = 0; m < 4; ++m)
#pragma unroll
        for (int n = 0; n < 4; ++n) acc[m][n] = {0.f, 0.f, 0.f, 0.f};

    const int c0 = tid, c1 = tid + 256;
    const int r0 = c0 & 127, k0off = (c0 >> 7) * 8;
    const int r1 = c1 & 127, k1off = (c1 >> 7) * 8;

    for (int k0 = 0; k0 < K; k0 += 32) {
        __syncthreads();
        gload16(A  + (size_t)(bm + r0) * K + k0 + k0off, &A_lds[c0 * 8]);
        gload16(A  + (size_t)(bm + r1) * K + k0 + k1off, &A_lds[c1 * 8]);
        gload16(Bm + (size_t)(bn + r0) * K + k0 + k0off, &B_lds[c0 * 8]);
        gload16(Bm + (size_t)(bn + r1) * K + k0 + k1off, &B_lds[c1 * 8]);
        __syncthreads();

        short8 af[4], bf[4];
#pragma unroll
        for (int m = 0; m < 4; ++m)
            af[m] = *reinterpret_cast<const short8*>(&A_lds[g * 1024 + (wr*64 + m*16 + ln16) * 8]);
#pragma unroll
        for (int n = 0; n < 4; ++n)
            bf[n] = *reinterpret_cast<const short8*>(&B_lds[g * 1024 + (wc*64 + n*16 + ln16) * 8]);
#pragma unroll
        for (int m = 0; m < 4; ++m)
#pragma unroll
            for (int n = 0; n < 4; ++n)
                acc[m][n] = mfma16(af[m], bf[n], acc[m][n]);
    }

#pragma unroll
    for (int m = 0; m < 4; ++m)
#pragma unroll
        for (int n = 0; n < 4; ++n)
#pragma unroll
            for (int r = 0; r < 4; ++r)
                store1<TC>(&C[(size_t)(bm + wr*64 + m*16 + g*4 + r) * N + bn + wc*64 + n*16 + ln16],
                           acc[m][n][r]);
}

// ---------------------------------------------------------------------------
// LayerNorm over L=512 per row, f32.
// ---------------------------------------------------------------------------
__global__ __launch_bounds__(256) void ln_kernel(const float* __restrict__ pre,
                                                 const float* __restrict__ w,
                                                 const float* __restrict__ bias,
                                                 float* __restrict__ out) {
    const int row = blockIdx.x;
    const int tid = threadIdx.x;
    __shared__ float red[256];
    const size_t base = (size_t)row * L_;
    float x0 = pre[base + tid];
    float x1 = pre[base + tid + 256];
    red[tid] = x0 + x1;
    __syncthreads();
    for (int o = 128; o; o >>= 1) { if (tid < o) red[tid] += red[tid + o]; __syncthreads(); }
    float mu = red[0] * (1.0f / L_);
    __syncthreads();
    float d0 = x0 - mu, d1 = x1 - mu;
    red[tid] = d0 * d0 + d1 * d1;
    __syncthreads();
    for (int o = 128; o; o >>= 1) { if (tid < o) red[tid] += red[tid + o]; __syncthreads(); }
    float rstd = rsqrtf(red[0] * (1.0f / L_) + 1e-5f);
    out[base + tid]       = d0 * rstd * w[tid]       + bias[tid];
    out[base + tid + 256] = d1 * rstd * w[tid + 256] + bias[tid + 256];
}

// ---------------------------------------------------------------------------
// f32 -> bf16 convert (4 elems/thread)
// ---------------------------------------------------------------------------
__global__ __launch_bounds__(256) void cvt_bf16(const float* __restrict__ in,
                                                u16* __restrict__ out) {
    size_t i = ((size_t)blockIdx.x * 256 + threadIdx.x) * 4;
    f32x4 v = *reinterpret_cast<const f32x4*>(&in[i]);
    u16x4 o; o[0]=f2bf(v[0]); o[1]=f2bf(v[1]); o[2]=f2bf(v[2]); o[3]=f2bf(v[3]);
    *reinterpret_cast<u16x4*>(&out[i]) = o;
}

// ---------------------------------------------------------------------------
// absorb: q'[hh][s][l] = sum_d qb[s][h0col + hh*128 + d] * Wuk[hh*128+d][l]
// ---------------------------------------------------------------------------
__global__ __launch_bounds__(256) void absorb(const u16* __restrict__ qb,
                                              const float* __restrict__ Wuk,
                                              u16* __restrict__ qp,
                                              int h0col) {
    const int st = blockIdx.x, lt = blockIdx.y, hh = blockIdx.z;
    const int tid = threadIdx.x;
    const int w = tid >> 6, l = tid & 63;
    const int g = l >> 4, ln16 = l & 15;

    __shared__ char A_lds[16384];
    __shared__ char B_lds[16384];

#pragma unroll
    for (int i = 0; i < 4; ++i) {
        int idx = tid + i * 256;
        int row = idx >> 4, c8 = idx & 15;
        int byte = (row * 256 + c8 * 16) ^ ((row & 7) << 4);
        *reinterpret_cast<u16x8*>(A_lds + byte) =
            *reinterpret_cast<const u16x8*>(qb + (size_t)(st*64 + row) * D_ + h0col + hh*128 + c8*8);
    }
#pragma unroll
    for (int i = 0; i < 32; ++i) {
        int idx = tid + i * 256;
        int k = idx >> 6, n = idx & 63;
        int byte = (n * 256 + k * 2) ^ ((n & 7) << 4);
        *reinterpret_cast<u16*>(B_lds + byte) =
            f2bf(Wuk[(size_t)(hh*128 + k) * L_ + lt*64 + n]);
    }
    __syncthreads();

    f32x4 acc[4];
#pragma unroll
    for (int a = 0; a < 4; ++a) acc[a] = {0,0,0,0};

#pragma unroll
    for (int kc = 0; kc < 4; ++kc) {
        const int arow = w*16 + ln16;
        short8 af = *reinterpret_cast<const short8*>(
            A_lds + ((arow*256 + kc*64 + g*16) ^ ((arow & 7) << 4)));
#pragma unroll
        for (int a = 0; a < 4; ++a) {
            const int brow = a*16 + ln16;
            short8 bf = *reinterpret_cast<const short8*>(
                B_lds + ((brow*256 + kc*64 + g*16) ^ ((brow & 7) << 4)));
            acc[a] = mfma16(af, bf, acc[a]);
        }
    }
#pragma unroll
    for (int a = 0; a < 4; ++a)
#pragma unroll
        for (int r = 0; r < 4; ++r)
            qp[((size_t)hh * S_ + st*64 + w*16 + g*4 + r) * L_ + lt*64 + a*16 + ln16] =
                f2bf(acc[a][r]);
}

// ---------------------------------------------------------------------------
// flash_split: grid (32 qt, 8 hh, 2 kv-chunk), block 256 (4 waves).
// Chunk c covers kv tiles [c*16, min(qt, c*16+15)].  Writes normalized
// partial ctx (bf16) + LSE (f32).  LDS 56 KB -> 2 blocks/CU.
// ---------------------------------------------------------------------------
__global__ __launch_bounds__(256) void flash_split(const u16* __restrict__ qp,
                                                   const u16* __restrict__ kbf,
                                                   const u16* __restrict__ vbf,
                                                   u16* __restrict__ opart,
                                                   float* __restrict__ ml,
                                                   int h0) {
    const int qt = 31 - blockIdx.x;      // heavy tiles first
    const int hh = blockIdx.y;
    const int c  = blockIdx.z;
    const int h  = h0 + hh;
    const int tid = threadIdx.x;
    const int w = tid >> 6, l = tid & 63;
    const int g = l >> 4, ln16 = l & 15;

    const int kt0 = c * 16;
    const int kt1 = min(qt, kt0 + 15);
    if (kt1 < kt0) {                      // empty chunk: mark LSE absent
        if (tid < 64) ml[(size_t)(c*8 + hh)*S_ + qt*64 + tid] = -3e38f;
        return;
    }

    __shared__ u16 K_lds[16384];          // 32 KB: [kslice 0..31][row 0..63][8]
    __shared__ char V_lds[16384];         // [dv 0..127][kv 0..63] u16, ^((dv&7)<<4)
    __shared__ char P_lds[8192];
    char* P_my = P_lds + w * 2048;

    short8 qreg[16];
    {
        const u16* qbase = qp + ((size_t)hh * S_ + qt*64 + w*16 + ln16) * L_ + g*8;
#pragma unroll
        for (int kc = 0; kc < 16; ++kc)
            qreg[kc] = *reinterpret_cast<const short8*>(qbase + kc*32);
    }

    float m_run = -3e38f, l_run = 0.f;
    f32x4 acc[8];
#pragma unroll
    for (int cb = 0; cb < 8; ++cb) acc[cb] = {0,0,0,0};

    const int sq = qt*64 + w*16 + ln16;
    const float scale = 0.08838834764831845f;

    for (int kt = kt0; kt <= kt1; ++kt) {
        __syncthreads();
        // ---- stage V transposed (conflict-free: lanes sweep kv)
        {
            const u16* vsrc = vbf + (size_t)kt * 64 * D_ + h * DH_;
            const int kv = tid & 63;
#pragma unroll
            for (int p = 0; p < 4; ++p) {
                int dg = (tid >> 6) + p * 4;
                u16x8 v8 = *reinterpret_cast<const u16x8*>(vsrc + (size_t)kv * D_ + dg*8);
#pragma unroll
                for (int j = 0; j < 8; ++j) {
                    int dv = dg*8 + j;
                    *reinterpret_cast<u16*>(V_lds + ((dv*128 + kv*2) ^ (j << 4))) = v8[j];
                }
            }
        }
        // ---- stage K half 0 (cols 0..255) via DMA
        const u16* ksrc = kbf + (size_t)kt * 64 * L_;
#pragma unroll
        for (int i = 0; i < 8; ++i) {
            int ch = tid + i * 256;
            int s = ch >> 6, row = ch & 63;
            gload16(ksrc + (size_t)row * L_ + s*8, &K_lds[ch * 8]);
        }
        __syncthreads();

        f32x4 sacc[4];
#pragma unroll
        for (int a = 0; a < 4; ++a) sacc[a] = {0,0,0,0};
#pragma unroll
        for (int a = 0; a < 4; ++a) {
            const int row = a*16 + ln16;
#pragma unroll
            for (int kc = 0; kc < 8; ++kc) {
                short8 kf = *reinterpret_cast<const short8*>(&K_lds[((kc*4 + g)*64 + row) * 8]);
                sacc[a] = mfma16(kf, qreg[kc], sacc[a]);
            }
        }
        __syncthreads();
        // ---- stage K half 1 (cols 256..511)
#pragma unroll
        for (int i = 0; i < 8; ++i) {
            int ch = tid + i * 256;
            int s = ch >> 6, row = ch & 63;
            gload16(ksrc + (size_t)row * L_ + 256 + s*8, &K_lds[ch * 8]);
        }
        __syncthreads();
#pragma unroll
        for (int a = 0; a < 4; ++a) {
            const int row = a*16 + ln16;
#pragma unroll
            for (int kc = 0; kc < 8; ++kc) {
                short8 kf = *reinterpret_cast<const short8*>(&K_lds[((kc*4 + g)*64 + row) * 8]);
                sacc[a] = mfma16(kf, qreg[8 + kc], sacc[a]);
            }
        }

        // ---- online softmax (lane owns q = ln16)
        float p[4][4];
        float tmax = -3e38f;
#pragma unroll
        for (int a = 0; a < 4; ++a)
#pragma unroll
            for (int r = 0; r < 4; ++r) {
                int t = kt*64 + a*16 + g*4 + r;
                float v = (t <= sq) ? sacc[a][r] * scale : -3e38f;
                p[a][r] = v;
                tmax = fmaxf(tmax, v);
            }
        tmax = fmaxf(tmax, __shfl_xor(tmax, 16, 64));
        tmax = fmaxf(tmax, __shfl_xor(tmax, 32, 64));
        float m_new = fmaxf(m_run, tmax);
        float fac = __expf(m_run - m_new);
        float rsum = 0.f;
#pragma unroll
        for (int a = 0; a < 4; ++a)
#pragma unroll
            for (int r = 0; r < 4; ++r) {
                float e = __expf(p[a][r] - m_new);
                p[a][r] = e;
                rsum += e;
            }
        rsum += __shfl_xor(rsum, 16, 64);
        rsum += __shfl_xor(rsum, 32, 64);
        l_run = l_run * fac + rsum;
        m_run = m_new;

        // ---- P -> wave-local LDS (bf16)
        {
            const int ps = (ln16 & 7) << 4;
#pragma unroll
            for (int a = 0; a < 4; ++a) {
                u16x4 quad;
#pragma unroll
                for (int r = 0; r < 4; ++r) quad[r] = f2bf(p[a][r]);
                *reinterpret_cast<u16x4*>(P_my + ((ln16*128 + a*32 + g*8) ^ ps)) = quad;
            }
        }
        // ---- rescale ctx
        float fr[4];
#pragma unroll
        for (int r = 0; r < 4; ++r) fr[r] = __shfl(fac, g*4 + r, 64);
#pragma unroll
        for (int cb = 0; cb < 8; ++cb)
#pragma unroll
            for (int r = 0; r < 4; ++r) acc[cb][r] *= fr[r];

        // ---- PV
#pragma unroll
        for (int kc2 = 0; kc2 < 2; ++kc2) {
            short8 pf = *reinterpret_cast<const short8*>(
                P_my + ((ln16*128 + kc2*64 + g*16) ^ ((ln16 & 7) << 4)));
#pragma unroll
            for (int cb = 0; cb < 8; ++cb) {
                const int dv = cb*16 + ln16;
                short8 vf = *reinterpret_cast<const short8*>(
                    V_lds + ((dv*128 + kc2*64 + g*16) ^ ((dv & 7) << 4)));
                acc[cb] = mfma16(pf, vf, acc[cb]);
            }
        }
    }

    // ---- epilogue: normalized partial + LSE
    float inv = 1.0f / l_run;
    float lse = m_run + __logf(l_run);
    float ir[4];
#pragma unroll
    for (int r = 0; r < 4; ++r) ir[r] = __shfl(inv, g*4 + r, 64);
#pragma unroll
    for (int cb = 0; cb < 8; ++cb)
#pragma unroll
        for (int r = 0; r < 4; ++r) {
            int q = qt*64 + w*16 + g*4 + r;
            opart[((size_t)(c*8 + hh)*S_ + q)*128 + cb*16 + ln16] = f2bf(acc[cb][r] * ir[r]);
        }
    if (g == 0) ml[(size_t)(c*8 + hh)*S_ + qt*64 + w*16 + ln16] = lse;
}

// ---------------------------------------------------------------------------
// combine: ctx = softmax-weighted blend of the two kv-chunk partials.
// ---------------------------------------------------------------------------
__global__ __launch_bounds__(256) void combine(const u16* __restrict__ opart,
                                               const float* __restrict__ ml,
                                               u16* __restrict__ ctx,
                                               int h0) {
    int t = blockIdx.x * 256 + threadIdx.x;
    int qh = t >> 4;
    int q = qh >> 3, hh = qh & 7;
    int dv0 = (t & 15) * 8;

    float lse0 = ml[(size_t)hh * S_ + q];
    float lse1 = ml[(size_t)(8 + hh) * S_ + q];
    u16x8 a = *reinterpret_cast<const u16x8*>(&opart[((size_t)hh*S_ + q)*128 + dv0]);
    float w0 = 1.f, w1 = 0.f;
    u16x8 b = a;
    if (lse1 > -1e37f) {
        float m = fmaxf(lse0, lse1);
        float e0 = __expf(lse0 - m), e1 = __expf(lse1 - m);
        float s = 1.0f / (e0 + e1);
        w0 = e0 * s; w1 = e1 * s;
        b = *reinterpret_cast<const u16x8*>(&opart[((size_t)(8 + hh)*S_ + q)*128 + dv0]);
    }
    u16x8 o;
#pragma unroll
    for (int j = 0; j < 8; ++j) o[j] = f2bf(w0 * bf2f(a[j]) + w1 * bf2f(b[j]));
    *reinterpret_cast<u16x8*>(&ctx[(size_t)q * D_ + (h0 + hh) * DH_ + dv0]) = o;
}

// ---------------------------------------------------------------------------
// ws (44 MB):
//   [ 0,16) xb_bf[0,8)+wslot[8,16) -> reused as qprime [0,16)
//   [16,24) qb_bf  [24,32) vb_bf  [32,36) ckv_bf (full M)  [36,44) ctx_bf
// d_out reuse: ckvp f32 in out_b1 region; flash partials (opart bf16 8MB +
// lse f32 128KB) in out_b region (dead until the final mgemm per batch).
// ---------------------------------------------------------------------------
extern "C" void kernel_launch(void* const* d_in, const int* in_sizes, int n_in,
                              void* d_out, int out_size, void* d_ws, size_t ws_size,
                              hipStream_t stream) {
    const float* x    = (const float*)d_in[0];
    const float* Wq   = (const float*)d_in[1];
    const float* Wdkv = (const float*)d_in[2];
    const float* Wuk  = (const float*)d_in[3];
    const float* Wuv  = (const float*)d_in[4];
    const float* Wo   = (const float*)d_in[5];
    const float* lnw  = (const float*)d_in[6];
    const float* lnb  = (const float*)d_in[7];

    float* out = (float*)d_out;
    float* ckv = out + (size_t)M_ * D_;
    float* ckvp = out + (size_t)S_ * D_;              // out_b1 region scratch

    char* ws = (char*)d_ws;
    u16* xb_bf  = (u16*)(ws);
    u16* wslot  = (u16*)(ws + (size_t)8388608);
    u16* qprime = (u16*)(ws);                          // overlaps xb+wslot
    u16* qb_bf  = (u16*)(ws + (size_t)16777216);
    u16* vb_bf  = (u16*)(ws + (size_t)25165824);
    u16* ckv_bf = (u16*)(ws + (size_t)33554432);
    u16* ctx_bf = (u16*)(ws + (size_t)37748736);

    dim3 blk(256);

    for (int b = 0; b < B_; ++b) {
        const float* xb     = x + (size_t)b * S_ * D_;
        float*       ckv_b  = ckv + (size_t)b * S_ * L_;
        u16*         ckvbf_b= ckv_bf + (size_t)b * S_ * L_;
        float*       outb   = out + (size_t)b * S_ * D_;
        u16*         opart  = (u16*)outb;                          // 8 MB
        float*       ml     = (float*)((char*)outb + 8388608);     // 128 KB

        cvt_bf16<<<dim3(4096), blk, 0, stream>>>(xb, xb_bf);

        cvt_bf16<<<dim3(1024), blk, 0, stream>>>(Wdkv, wslot);
        mgemm<float><<<dim3(L_/128, S_/128), blk, 0, stream>>>(xb_bf, wslot, ckvp, L_, D_);
        ln_kernel<<<dim3(S_), blk, 0, stream>>>(ckvp, lnw, lnb, ckv_b);
        cvt_bf16<<<dim3(1024), blk, 0, stream>>>(ckv_b, ckvbf_b);

        cvt_bf16<<<dim3(4096), blk, 0, stream>>>(Wq, wslot);
        mgemm<u16><<<dim3(D_/128, S_/128), blk, 0, stream>>>(xb_bf, wslot, qb_bf, D_, D_);

        cvt_bf16<<<dim3(1024), blk, 0, stream>>>(Wuv, wslot);
        mgemm<u16><<<dim3(D_/128, S_/128), blk, 0, stream>>>(ckvbf_b, wslot, vb_bf, D_, L_);

        for (int hc = 0; hc < 2; ++hc) {
            absorb<<<dim3(S_/64, L_/64, 8), blk, 0, stream>>>(
                qb_bf, Wuk + (size_t)hc * 8 * DH_ * L_, qprime, hc * 8 * DH_);
            flash_split<<<dim3(S_/64, 8, 2), blk, 0, stream>>>(
                qprime, ckvbf_b, vb_bf, opart, ml, hc * 8);
            combine<<<dim3(1024), blk, 0, stream>>>(opart, ml, ctx_bf, hc * 8);
        }

        cvt_bf16<<<dim3(4096), blk, 0, stream>>>(Wo, wslot);
        mgemm<float><<<dim3(D_/128, S_/128), blk, 0, stream>>>(ctx_bf, wslot, outb, D_, D_);
    }
}

// Round 11
// 907.464 us; speedup vs baseline: 20.5196x; 1.0765x over previous
//
#include <hip/hip_runtime.h>

#define B_  2
#define S_  2048
#define D_  2048
#define H_  16
#define DH_ 128
#define L_  512
#define M_  (B_*S_)

typedef unsigned short u16;
typedef float f32x4 __attribute__((ext_vector_type(4)));
typedef short short8 __attribute__((ext_vector_type(8)));
typedef u16 u16x4 __attribute__((ext_vector_type(4)));
typedef u16 u16x8 __attribute__((ext_vector_type(8)));

__device__ inline float bf2f(u16 u) {
    union { unsigned int i; float f; } x; x.i = ((unsigned int)u) << 16; return x.f;
}
__device__ inline u16 f2bf(float f) {
    union { float f; unsigned int i; } x; x.f = f;
    unsigned int r = x.i + 0x7FFFu + ((x.i >> 16) & 1u);
    return (u16)(r >> 16);
}
__device__ inline f32x4 mfma16(short8 a, short8 b, f32x4 c) {
    return __builtin_amdgcn_mfma_f32_16x16x32_bf16(a, b, c, 0, 0, 0);
}

typedef const __attribute__((address_space(1))) unsigned int gu32;
typedef __attribute__((address_space(3))) unsigned int lu32;
__device__ inline void gload16(const u16* g, u16* l) {
    __builtin_amdgcn_global_load_lds((gu32*)g, (lu32*)l, 16, 0, 0);
}

template <typename T> __device__ inline void store1(T* p, float v);
template <> __device__ inline void store1<float>(float* p, float v) { *p = v; }
template <> __device__ inline void store1<u16>(u16* p, float v) { *p = f2bf(v); }

// ---------------------------------------------------------------------------
// MFMA GEMM: C[M][N] = A[M][K] @ B[N][K]^T, A/B bf16, f32 accum, TC out.
// 128x128 tile, 4 waves, BK=32, global_load_lds, k-slice LDS layout.
// ---------------------------------------------------------------------------
template <typename TC>
__global__ __launch_bounds__(256) void mgemm(const u16* __restrict__ A,
                                             const u16* __restrict__ Bm,
                                             TC* __restrict__ C,
                                             int N, int K) {
    const int tid = threadIdx.x;
    const int bn = blockIdx.x * 128, bm = blockIdx.y * 128;
    const int w = tid >> 6, l = tid & 63;
    const int wr = w >> 1, wc = w & 1;
    const int g = l >> 4, ln16 = l & 15;

    __shared__ u16 A_lds[4096];     // [koff][row][8]
    __shared__ u16 B_lds[4096];

    f32x4 acc[4][4];
#pragma unroll
    for (int m = 0; m < 4; ++m)
#pragma unroll
        for (int n = 0; n < 4; ++n) acc[m][n] = {0.f, 0.f, 0.f, 0.f};

    const int c0 = tid, c1 = tid + 256;
    const int r0 = c0 & 127, k0off = (c0 >> 7) * 8;
    const int r1 = c1 & 127, k1off = (c1 >> 7) * 8;

    for (int k0 = 0; k0 < K; k0 += 32) {
        __syncthreads();
        gload16(A  + (size_t)(bm + r0) * K + k0 + k0off, &A_lds[c0 * 8]);
        gload16(A  + (size_t)(bm + r1) * K + k0 + k1off, &A_lds[c1 * 8]);
        gload16(Bm + (size_t)(bn + r0) * K + k0 + k0off, &B_lds[c0 * 8]);
        gload16(Bm + (size_t)(bn + r1) * K + k0 + k1off, &B_lds[c1 * 8]);
        __syncthreads();

        short8 af[4], bf[4];
#pragma unroll
        for (int m = 0; m < 4; ++m)
            af[m] = *reinterpret_cast<const short8*>(&A_lds[g * 1024 + (wr*64 + m*16 + ln16) * 8]);
#pragma unroll
        for (int n = 0; n < 4; ++n)
            bf[n] = *reinterpret_cast<const short8*>(&B_lds[g * 1024 + (wc*64 + n*16 + ln16) * 8]);
#pragma unroll
        for (int m = 0; m < 4; ++m)
#pragma unroll
            for (int n = 0; n < 4; ++n)
                acc[m][n] = mfma16(af[m], bf[n], acc[m][n]);
    }

#pragma unroll
    for (int m = 0; m < 4; ++m)
#pragma unroll
        for (int n = 0; n < 4; ++n)
#pragma unroll
            for (int r = 0; r < 4; ++r)
                store1<TC>(&C[(size_t)(bm + wr*64 + m*16 + g*4 + r) * N + bn + wc*64 + n*16 + ln16],
                           acc[m][n][r]);
}

// ---------------------------------------------------------------------------
// LayerNorm over L=512 per row, f32.
// ---------------------------------------------------------------------------
__global__ __launch_bounds__(256) void ln_kernel(const float* __restrict__ pre,
                                                 const float* __restrict__ w,
                                                 const float* __restrict__ bias,
                                                 float* __restrict__ out) {
    const int row = blockIdx.x;
    const int tid = threadIdx.x;
    __shared__ float red[256];
    const size_t base = (size_t)row * L_;
    float x0 = pre[base + tid];
    float x1 = pre[base + tid + 256];
    red[tid] = x0 + x1;
    __syncthreads();
    for (int o = 128; o; o >>= 1) { if (tid < o) red[tid] += red[tid + o]; __syncthreads(); }
    float mu = red[0] * (1.0f / L_);
    __syncthreads();
    float d0 = x0 - mu, d1 = x1 - mu;
    red[tid] = d0 * d0 + d1 * d1;
    __syncthreads();
    for (int o = 128; o; o >>= 1) { if (tid < o) red[tid] += red[tid + o]; __syncthreads(); }
    float rstd = rsqrtf(red[0] * (1.0f / L_) + 1e-5f);
    out[base + tid]       = d0 * rstd * w[tid]       + bias[tid];
    out[base + tid + 256] = d1 * rstd * w[tid + 256] + bias[tid + 256];
}

// ---------------------------------------------------------------------------
// f32 -> bf16 convert (4 elems/thread)
// ---------------------------------------------------------------------------
__global__ __launch_bounds__(256) void cvt_bf16(const float* __restrict__ in,
                                                u16* __restrict__ out) {
    size_t i = ((size_t)blockIdx.x * 256 + threadIdx.x) * 4;
    f32x4 v = *reinterpret_cast<const f32x4*>(&in[i]);
    u16x4 o; o[0]=f2bf(v[0]); o[1]=f2bf(v[1]); o[2]=f2bf(v[2]); o[3]=f2bf(v[3]);
    *reinterpret_cast<u16x4*>(&out[i]) = o;
}

// ---------------------------------------------------------------------------
// absorb: q'[hh][s][l] = sum_d qb[s][h0col + hh*128 + d] * Wuk[hh*128+d][l]
// ---------------------------------------------------------------------------
__global__ __launch_bounds__(256) void absorb(const u16* __restrict__ qb,
                                              const float* __restrict__ Wuk,
                                              u16* __restrict__ qp,
                                              int h0col) {
    const int st = blockIdx.x, lt = blockIdx.y, hh = blockIdx.z;
    const int tid = threadIdx.x;
    const int w = tid >> 6, l = tid & 63;
    const int g = l >> 4, ln16 = l & 15;

    __shared__ char A_lds[16384];
    __shared__ char B_lds[16384];

#pragma unroll
    for (int i = 0; i < 4; ++i) {
        int idx = tid + i * 256;
        int row = idx >> 4, c8 = idx & 15;
        int byte = (row * 256 + c8 * 16) ^ ((row & 7) << 4);
        *reinterpret_cast<u16x8*>(A_lds + byte) =
            *reinterpret_cast<const u16x8*>(qb + (size_t)(st*64 + row) * D_ + h0col + hh*128 + c8*8);
    }
#pragma unroll
    for (int i = 0; i < 32; ++i) {
        int idx = tid + i * 256;
        int k = idx >> 6, n = idx & 63;
        int byte = (n * 256 + k * 2) ^ ((n & 7) << 4);
        *reinterpret_cast<u16*>(B_lds + byte) =
            f2bf(Wuk[(size_t)(hh*128 + k) * L_ + lt*64 + n]);
    }
    __syncthreads();

    f32x4 acc[4];
#pragma unroll
    for (int a = 0; a < 4; ++a) acc[a] = {0,0,0,0};

#pragma unroll
    for (int kc = 0; kc < 4; ++kc) {
        const int arow = w*16 + ln16;
        short8 af = *reinterpret_cast<const short8*>(
            A_lds + ((arow*256 + kc*64 + g*16) ^ ((arow & 7) << 4)));
#pragma unroll
        for (int a = 0; a < 4; ++a) {
            const int brow = a*16 + ln16;
            short8 bf = *reinterpret_cast<const short8*>(
                B_lds + ((brow*256 + kc*64 + g*16) ^ ((brow & 7) << 4)));
            acc[a] = mfma16(af, bf, acc[a]);
        }
    }
#pragma unroll
    for (int a = 0; a < 4; ++a)
#pragma unroll
        for (int r = 0; r < 4; ++r)
            qp[((size_t)hh * S_ + st*64 + w*16 + g*4 + r) * L_ + lt*64 + a*16 + ln16] =
                f2bf(acc[a][r]);
}

// ---------------------------------------------------------------------------
// flash_split: grid (16 qt2, 8 hh, 4 kv-chunk), block 512 (8 waves, QBLK=128).
// Chunk c covers kv tiles [c*8, min(2*qt2+1, c*8+7)] (64-row tiles).
// 8 waves share one staged K/V tile -> 2x staging/barrier amortization.
// LDS 64 KB (K 32 + V 16 + P 16) -> 2 blocks/CU, 16 waves/CU.
// Writes normalized partial ctx (bf16) + LSE (f32); empty chunk -> LSE=-3e38.
// ---------------------------------------------------------------------------
__global__ __launch_bounds__(512) void flash_split(const u16* __restrict__ qp,
                                                   const u16* __restrict__ kbf,
                                                   const u16* __restrict__ vbf,
                                                   u16* __restrict__ opart,
                                                   float* __restrict__ ml,
                                                   int h0) {
    const int qt2 = 15 - blockIdx.x;     // heavy tiles first
    const int hh = blockIdx.y;
    const int c  = blockIdx.z;
    const int h  = h0 + hh;
    const int tid = threadIdx.x;
    const int w = tid >> 6, l = tid & 63;
    const int g = l >> 4, ln16 = l & 15;

    const int kt0 = c * 8;
    const int kt1 = min(2*qt2 + 1, kt0 + 7);
    if (kt1 < kt0) {                      // empty chunk: mark LSE absent
        if (tid < 128) ml[(size_t)(c*8 + hh)*S_ + qt2*128 + tid] = -3e38f;
        return;
    }

    __shared__ u16 K_lds[16384];          // 32 KB: [kslice 0..31][row 0..63][8]
    __shared__ char V_lds[16384];         // [dv 0..127][kv 0..63] u16, ^swz
    __shared__ char P_lds[16384];         // 8 waves x 2 KB
    char* P_my = P_lds + w * 2048;

    short8 qreg[16];
    {
        const u16* qbase = qp + ((size_t)hh * S_ + qt2*128 + w*16 + ln16) * L_ + g*8;
#pragma unroll
        for (int kc = 0; kc < 16; ++kc)
            qreg[kc] = *reinterpret_cast<const short8*>(qbase + kc*32);
    }

    float m_run = -3e38f, l_run = 0.f;
    f32x4 acc[8];
#pragma unroll
    for (int cb = 0; cb < 8; ++cb) acc[cb] = {0,0,0,0};

    const int sq = qt2*128 + w*16 + ln16;
    const float scale = 0.08838834764831845f;

    for (int kt = kt0; kt <= kt1; ++kt) {
        __syncthreads();
        // ---- stage V transposed (lanes sweep kv -> contiguous stores)
        {
            const u16* vsrc = vbf + (size_t)kt * 64 * D_ + h * DH_;
            const int kv = tid & 63;
#pragma unroll
            for (int p = 0; p < 2; ++p) {
                int dg = (tid >> 6) + p * 8;
                u16x8 v8 = *reinterpret_cast<const u16x8*>(vsrc + (size_t)kv * D_ + dg*8);
#pragma unroll
                for (int j = 0; j < 8; ++j) {
                    int dv = dg*8 + j;
                    *reinterpret_cast<u16*>(V_lds + ((dv*128 + kv*2) ^ (j << 4))) = v8[j];
                }
            }
        }
        // ---- stage K half 0 (cols 0..255) via DMA
        const u16* ksrc = kbf + (size_t)kt * 64 * L_;
#pragma unroll
        for (int i = 0; i < 4; ++i) {
            int ch = tid + i * 512;
            int s = ch >> 6, row = ch & 63;
            gload16(ksrc + (size_t)row * L_ + s*8, &K_lds[ch * 8]);
        }
        __syncthreads();

        f32x4 sacc[4];
#pragma unroll
        for (int a = 0; a < 4; ++a) sacc[a] = {0,0,0,0};
#pragma unroll
        for (int a = 0; a < 4; ++a) {
            const int row = a*16 + ln16;
#pragma unroll
            for (int kc = 0; kc < 8; ++kc) {
                short8 kf = *reinterpret_cast<const short8*>(&K_lds[((kc*4 + g)*64 + row) * 8]);
                sacc[a] = mfma16(kf, qreg[kc], sacc[a]);
            }
        }
        __syncthreads();
        // ---- stage K half 1 (cols 256..511)
#pragma unroll
        for (int i = 0; i < 4; ++i) {
            int ch = tid + i * 512;
            int s = ch >> 6, row = ch & 63;
            gload16(ksrc + (size_t)row * L_ + 256 + s*8, &K_lds[ch * 8]);
        }
        __syncthreads();
#pragma unroll
        for (int a = 0; a < 4; ++a) {
            const int row = a*16 + ln16;
#pragma unroll
            for (int kc = 0; kc < 8; ++kc) {
                short8 kf = *reinterpret_cast<const short8*>(&K_lds[((kc*4 + g)*64 + row) * 8]);
                sacc[a] = mfma16(kf, qreg[8 + kc], sacc[a]);
            }
        }

        // ---- online softmax (lane owns q = ln16)
        float p[4][4];
        float tmax = -3e38f;
#pragma unroll
        for (int a = 0; a < 4; ++a)
#pragma unroll
            for (int r = 0; r < 4; ++r) {
                int t = kt*64 + a*16 + g*4 + r;
                float v = (t <= sq) ? sacc[a][r] * scale : -3e38f;
                p[a][r] = v;
                tmax = fmaxf(tmax, v);
            }
        tmax = fmaxf(tmax, __shfl_xor(tmax, 16, 64));
        tmax = fmaxf(tmax, __shfl_xor(tmax, 32, 64));
        float m_new = fmaxf(m_run, tmax);
        float fac = __expf(m_run - m_new);
        float rsum = 0.f;
#pragma unroll
        for (int a = 0; a < 4; ++a)
#pragma unroll
            for (int r = 0; r < 4; ++r) {
                float e = __expf(p[a][r] - m_new);
                p[a][r] = e;
                rsum += e;
            }
        rsum += __shfl_xor(rsum, 16, 64);
        rsum += __shfl_xor(rsum, 32, 64);
        l_run = l_run * fac + rsum;
        m_run = m_new;

        // ---- P -> wave-local LDS (bf16)
        {
            const int ps = (ln16 & 7) << 4;
#pragma unroll
            for (int a = 0; a < 4; ++a) {
                u16x4 quad;
#pragma unroll
                for (int r = 0; r < 4; ++r) quad[r] = f2bf(p[a][r]);
                *reinterpret_cast<u16x4*>(P_my + ((ln16*128 + a*32 + g*8) ^ ps)) = quad;
            }
        }
        // ---- rescale ctx
        float fr[4];
#pragma unroll
        for (int r = 0; r < 4; ++r) fr[r] = __shfl(fac, g*4 + r, 64);
#pragma unroll
        for (int cb = 0; cb < 8; ++cb)
#pragma unroll
            for (int r = 0; r < 4; ++r) acc[cb][r] *= fr[r];

        // ---- PV
#pragma unroll
        for (int kc2 = 0; kc2 < 2; ++kc2) {
            short8 pf = *reinterpret_cast<const short8*>(
                P_my + ((ln16*128 + kc2*64 + g*16) ^ ((ln16 & 7) << 4)));
#pragma unroll
            for (int cb = 0; cb < 8; ++cb) {
                const int dv = cb*16 + ln16;
                short8 vf = *reinterpret_cast<const short8*>(
                    V_lds + ((dv*128 + kc2*64 + g*16) ^ ((dv & 7) << 4)));
                acc[cb] = mfma16(pf, vf, acc[cb]);
            }
        }
    }

    // ---- epilogue: normalized partial + LSE
    float inv = 1.0f / l_run;
    float lse = m_run + __logf(l_run);
    float ir[4];
#pragma unroll
    for (int r = 0; r < 4; ++r) ir[r] = __shfl(inv, g*4 + r, 64);
#pragma unroll
    for (int cb = 0; cb < 8; ++cb)
#pragma unroll
        for (int r = 0; r < 4; ++r) {
            int q = qt2*128 + w*16 + g*4 + r;
            opart[((size_t)(c*8 + hh)*S_ + q)*128 + cb*16 + ln16] = f2bf(acc[cb][r] * ir[r]);
        }
    if (g == 0) ml[(size_t)(c*8 + hh)*S_ + qt2*128 + w*16 + ln16] = lse;
}

// ---------------------------------------------------------------------------
// combine: ctx = LSE-weighted blend of the 4 kv-chunk partials.
// Empty chunks carry lse=-3e38 -> weight exp() underflows to exactly 0.
// ---------------------------------------------------------------------------
__global__ __launch_bounds__(256) void combine(const u16* __restrict__ opart,
                                               const float* __restrict__ ml,
                                               u16* __restrict__ ctx,
                                               int h0) {
    int t = blockIdx.x * 256 + threadIdx.x;
    int qh = t >> 4;
    int q = qh >> 3, hh = qh & 7;
    int dv0 = (t & 15) * 8;

    float ls[4], m = -3e38f;
#pragma unroll
    for (int c = 0; c < 4; ++c) {
        ls[c] = ml[(size_t)(c*8 + hh) * S_ + q];
        m = fmaxf(m, ls[c]);
    }
    float e[4], s = 0.f;
#pragma unroll
    for (int c = 0; c < 4; ++c) { e[c] = __expf(ls[c] - m); s += e[c]; }
    float is = 1.0f / s;

    float accv[8] = {};
#pragma unroll
    for (int c = 0; c < 4; ++c) {
        if (e[c] > 0.f) {
            u16x8 a = *reinterpret_cast<const u16x8*>(
                &opart[((size_t)(c*8 + hh)*S_ + q)*128 + dv0]);
#pragma unroll
            for (int j = 0; j < 8; ++j) accv[j] += e[c] * bf2f(a[j]);
        }
    }
    u16x8 o;
#pragma unroll
    for (int j = 0; j < 8; ++j) o[j] = f2bf(accv[j] * is);
    *reinterpret_cast<u16x8*>(&ctx[(size_t)q * D_ + (h0 + hh) * DH_ + dv0]) = o;
}

// ---------------------------------------------------------------------------
// ws (44.25 MB of proven 48):
//   [ 0,16) xb_bf[0,8)+wslot[8,16) -> reused as qprime [0,16)
//   [16,24) qb_bf  [24,32) vb_bf  [32,36) ckv_bf (full M)  [36,44) ctx_bf
//   [44,44.25) ml (4 chunks x 8 hh x S f32)
// d_out reuse: ckvp f32 in out_b1 region; opart (16 MB bf16) in out_b region
// (dead until the final mgemm per batch).
// ---------------------------------------------------------------------------
extern "C" void kernel_launch(void* const* d_in, const int* in_sizes, int n_in,
                              void* d_out, int out_size, void* d_ws, size_t ws_size,
                              hipStream_t stream) {
    const float* x    = (const float*)d_in[0];
    const float* Wq   = (const float*)d_in[1];
    const float* Wdkv = (const float*)d_in[2];
    const float* Wuk  = (const float*)d_in[3];
    const float* Wuv  = (const float*)d_in[4];
    const float* Wo   = (const float*)d_in[5];
    const float* lnw  = (const float*)d_in[6];
    const float* lnb  = (const float*)d_in[7];

    float* out = (float*)d_out;
    float* ckv = out + (size_t)M_ * D_;
    float* ckvp = out + (size_t)S_ * D_;              // out_b1 region scratch

    char* ws = (char*)d_ws;
    u16* xb_bf  = (u16*)(ws);
    u16* wslot  = (u16*)(ws + (size_t)8388608);
    u16* qprime = (u16*)(ws);                          // overlaps xb+wslot
    u16* qb_bf  = (u16*)(ws + (size_t)16777216);
    u16* vb_bf  = (u16*)(ws + (size_t)25165824);
    u16* ckv_bf = (u16*)(ws + (size_t)33554432);
    u16* ctx_bf = (u16*)(ws + (size_t)37748736);
    float* ml   = (float*)(ws + (size_t)46137344);     // 256 KB

    dim3 blk(256);

    for (int b = 0; b < B_; ++b) {
        const float* xb     = x + (size_t)b * S_ * D_;
        float*       ckv_b  = ckv + (size_t)b * S_ * L_;
        u16*         ckvbf_b= ckv_bf + (size_t)b * S_ * L_;
        float*       outb   = out + (size_t)b * S_ * D_;
        u16*         opart  = (u16*)outb;                          // 16 MB

        cvt_bf16<<<dim3(4096), blk, 0, stream>>>(xb, xb_bf);

        cvt_bf16<<<dim3(1024), blk, 0, stream>>>(Wdkv, wslot);
        mgemm<float><<<dim3(L_/128, S_/128), blk, 0, stream>>>(xb_bf, wslot, ckvp, L_, D_);
        ln_kernel<<<dim3(S_), blk, 0, stream>>>(ckvp, lnw, lnb, ckv_b);
        cvt_bf16<<<dim3(1024), blk, 0, stream>>>(ckv_b, ckvbf_b);

        cvt_bf16<<<dim3(4096), blk, 0, stream>>>(Wq, wslot);
        mgemm<u16><<<dim3(D_/128, S_/128), blk, 0, stream>>>(xb_bf, wslot, qb_bf, D_, D_);

        cvt_bf16<<<dim3(1024), blk, 0, stream>>>(Wuv, wslot);
        mgemm<u16><<<dim3(D_/128, S_/128), blk, 0, stream>>>(ckvbf_b, wslot, vb_bf, D_, L_);

        for (int hc = 0; hc < 2; ++hc) {
            absorb<<<dim3(S_/64, L_/64, 8), blk, 0, stream>>>(
                qb_bf, Wuk + (size_t)hc * 8 * DH_ * L_, qprime, hc * 8 * DH_);
            flash_split<<<dim3(16, 8, 4), dim3(512), 0, stream>>>(
                qprime, ckvbf_b, vb_bf, opart, ml, hc * 8);
            combine<<<dim3(1024), blk, 0, stream>>>(opart, ml, ctx_bf, hc * 8);
        }

        cvt_bf16<<<dim3(4096), blk, 0, stream>>>(Wo, wslot);
        mgemm<float><<<dim3(D_/128, S_/128), blk, 0, stream>>>(ctx_bf, wslot, outb, D_, D_);
    }
}